// Round 5
// baseline (280.302 us; speedup 1.0000x reference)
//
#include <hip/hip_runtime.h>

// GlobalMaxAvgPool: segment max + segment mean, N=2e6, C=128, B=32, ids sorted.
// Memory-bound: 1.025 GB read -> floor ~164 us @ 6.3 TB/s.
// R5: two kernels only. gp_main inlines the boundary binary-search (33 lanes
// per block, overlapped across 2048 blocks), walks WAVE-CONTIGUOUS row ranges
// with an 8-deep nontemporal float4 unroll, and emits per-wave partials via
// __shfl_xor combine + plain stores (no LDS reduce, no hot-loop barriers,
// zero atomics). gp_reduce (32 blocks) combines contiguous slot ranges
// deterministically and writes all of d_out.

using f32x4 = __attribute__((ext_vector_type(4))) float;
#define INFF __builtin_huge_valf()

#define BLOCKS 2048
#define WPB    4                    // waves per block
#define NWAVES (BLOCKS * WPB)       // 8192
#define MAXR   4                    // max segment-runs per wave (data: <=2)

// ws layout: hdr[NWAVES*MAXR] ints at 0; partials at 1 MB (33.5 MB used)
#define OFF_PART (1u << 20)

__device__ __forceinline__ int lower_bound_i(const int* __restrict__ a, int n, int v) {
    int lo = 0, hi = n;
    while (lo < hi) {
        int mid = (lo + hi) >> 1;
        if (a[mid] < v) lo = mid + 1; else hi = mid;
    }
    return lo;
}

// C==128: 32 lanes x float4 = one row; wave covers 2 rows/step (1KB), walks a
// contiguous waveChunk-row range. Boundaries computed per block (L2-overlapped).
__global__ __launch_bounds__(256, 4)
void gp_main(const float* __restrict__ feat,
             const int* __restrict__ ids,
             int* __restrict__ hdr, float* __restrict__ part,
             int N, int waveChunk, int B) {
    const int t     = threadIdx.x;
    const int wv    = t >> 6;          // wave in block, 0..3
    const int lane  = t & 63;
    const int slot2 = (t >> 5) & 1;    // row parity within wave
    const int lane5 = t & 31;

    __shared__ int sb[33];
    if (t < 33) sb[t] = lower_bound_i(ids, N, t);   // sb[32]==N
    __syncthreads();

    const int w  = blockIdx.x * WPB + wv;           // global wave id
    int ws = w * waveChunk;
    int we = ws + waveChunk;
    if (we > N) we = N;

    if (ws < we) {
        // segment containing ws (uniform per wave)
        int seg = 0;
        #pragma unroll
        for (int s = 1; s < 33; ++s)
            if (sb[s] <= ws) seg = s;

        const f32x4* __restrict__ frow = reinterpret_cast<const f32x4*>(feat);

        int run = 0;
        int rs  = ws;
        while (rs < we && run < MAXR) {
            int re = sb[seg + 1];
            if (re > we) re = we;

            f32x4 vmax = {-INFF, -INFF, -INFF, -INFF};
            f32x4 vsum = {0.f, 0.f, 0.f, 0.f};
            int r = rs + slot2;
            for (; r + 14 < re; r += 16) {          // 8 loads in flight (8KB/wave)
                size_t b0 = (size_t)r * 32 + lane5;
                f32x4 f0 = __builtin_nontemporal_load(&frow[b0 +   0]);
                f32x4 f1 = __builtin_nontemporal_load(&frow[b0 +  64]);
                f32x4 f2 = __builtin_nontemporal_load(&frow[b0 + 128]);
                f32x4 f3 = __builtin_nontemporal_load(&frow[b0 + 192]);
                f32x4 f4 = __builtin_nontemporal_load(&frow[b0 + 256]);
                f32x4 f5 = __builtin_nontemporal_load(&frow[b0 + 320]);
                f32x4 f6 = __builtin_nontemporal_load(&frow[b0 + 384]);
                f32x4 f7 = __builtin_nontemporal_load(&frow[b0 + 448]);
                vmax[0]=fmaxf(vmax[0],f0[0]); vmax[1]=fmaxf(vmax[1],f0[1]);
                vmax[2]=fmaxf(vmax[2],f0[2]); vmax[3]=fmaxf(vmax[3],f0[3]); vsum+=f0;
                vmax[0]=fmaxf(vmax[0],f1[0]); vmax[1]=fmaxf(vmax[1],f1[1]);
                vmax[2]=fmaxf(vmax[2],f1[2]); vmax[3]=fmaxf(vmax[3],f1[3]); vsum+=f1;
                vmax[0]=fmaxf(vmax[0],f2[0]); vmax[1]=fmaxf(vmax[1],f2[1]);
                vmax[2]=fmaxf(vmax[2],f2[2]); vmax[3]=fmaxf(vmax[3],f2[3]); vsum+=f2;
                vmax[0]=fmaxf(vmax[0],f3[0]); vmax[1]=fmaxf(vmax[1],f3[1]);
                vmax[2]=fmaxf(vmax[2],f3[2]); vmax[3]=fmaxf(vmax[3],f3[3]); vsum+=f3;
                vmax[0]=fmaxf(vmax[0],f4[0]); vmax[1]=fmaxf(vmax[1],f4[1]);
                vmax[2]=fmaxf(vmax[2],f4[2]); vmax[3]=fmaxf(vmax[3],f4[3]); vsum+=f4;
                vmax[0]=fmaxf(vmax[0],f5[0]); vmax[1]=fmaxf(vmax[1],f5[1]);
                vmax[2]=fmaxf(vmax[2],f5[2]); vmax[3]=fmaxf(vmax[3],f5[3]); vsum+=f5;
                vmax[0]=fmaxf(vmax[0],f6[0]); vmax[1]=fmaxf(vmax[1],f6[1]);
                vmax[2]=fmaxf(vmax[2],f6[2]); vmax[3]=fmaxf(vmax[3],f6[3]); vsum+=f6;
                vmax[0]=fmaxf(vmax[0],f7[0]); vmax[1]=fmaxf(vmax[1],f7[1]);
                vmax[2]=fmaxf(vmax[2],f7[2]); vmax[3]=fmaxf(vmax[3],f7[3]); vsum+=f7;
            }
            for (; r < re; r += 2) {
                f32x4 f = __builtin_nontemporal_load(&frow[(size_t)r * 32 + lane5]);
                vmax[0]=fmaxf(vmax[0],f[0]); vmax[1]=fmaxf(vmax[1],f[1]);
                vmax[2]=fmaxf(vmax[2],f[2]); vmax[3]=fmaxf(vmax[3],f[3]); vsum+=f;
            }

            // combine slot2 halves in-register: lane l <-> l^32
            #pragma unroll
            for (int k = 0; k < 4; ++k) {
                vmax[k] = fmaxf(vmax[k], __shfl_xor(vmax[k], 32));
                vsum[k] += __shfl_xor(vsum[k], 32);
            }
            // wave partial: 128 max | 128 sum (plain contiguous stores)
            size_t base = (size_t)(w * MAXR + run) * 256;
            float* p = &part[base + slot2 * 128 + lane5 * 4];
            if (slot2 == 0) { p[0]=vmax[0]; p[1]=vmax[1]; p[2]=vmax[2]; p[3]=vmax[3]; }
            else            { p[0]=vsum[0]; p[1]=vsum[1]; p[2]=vsum[2]; p[3]=vsum[3]; }
            if (lane == 0) hdr[w * MAXR + run] = seg;

            ++run; ++seg; rs = re;
        }
        if (lane == 0)
            for (int rr = run; rr < MAXR; ++rr) hdr[w * MAXR + rr] = -1;
    } else if (lane == 0) {
        for (int rr = 0; rr < MAXR; ++rr) hdr[w * MAXR + rr] = -1;
    }
}

// One block per segment; slots for segment b are waves [s0/waveChunk,(s1-1)/waveChunk].
// Fixed scan order -> deterministic. Writes ALL of d_out.
__global__ void gp_reduce(const int* __restrict__ ids, int N,
                          const int* __restrict__ hdr,
                          const float* __restrict__ part,
                          float* __restrict__ out, int waveChunk) {
    __shared__ int sseg[2];
    int b = blockIdx.x;
    int t = threadIdx.x;            // t<128: max chan t ; t>=128: sum chan t-128
    if (t < 2) sseg[t] = lower_bound_i(ids, N, b + t);
    __syncthreads();
    int s0 = sseg[0], s1 = sseg[1];
    int cnt = s1 - s0;
    float m  = -INFF;
    float su = 0.f;
    if (cnt > 0) {
        int kw0 = s0 / waveChunk;
        int kw1 = (s1 - 1) / waveChunk;
        for (int kw = kw0; kw <= kw1; ++kw) {
            #pragma unroll
            for (int r = 0; r < MAXR; ++r) {
                if (hdr[kw * MAXR + r] == b) {
                    float v = part[(size_t)(kw * MAXR + r) * 256 + t];
                    m   = fmaxf(m, v);   // meaningful when t<128
                    su += v;             // meaningful when t>=128
                }
            }
        }
    }
    out[b * 256 + t] = (t < 128) ? m : su / fmaxf((float)cnt, 1.0f);
}

extern "C" void kernel_launch(void* const* d_in, const int* in_sizes, int n_in,
                              void* d_out, int out_size, void* d_ws, size_t ws_size,
                              hipStream_t stream) {
    const float* feat = (const float*)d_in[0];
    const int*   ids  = (const int*)d_in[1];
    int N = in_sizes[1];
    int C = (N > 0) ? (in_sizes[0] / N) : 128;   // 128
    int B = out_size / (2 * C);                  // 32
    float* out_f = (float*)d_out;

    char*  wsb  = (char*)d_ws;
    int*   hdr  = (int*)wsb;                     // NWAVES*MAXR ints (128 KB)
    float* part = (float*)(wsb + OFF_PART);      // NWAVES*MAXR*256 floats (32 MB)

    int waveChunk = (N + NWAVES - 1) / NWAVES;
    waveChunk = (waveChunk + 1) & ~1;            // even -> aligned 1KB wave steps

    gp_main<<<BLOCKS, 256, 0, stream>>>(feat, ids, hdr, part, N, waveChunk, B);
    gp_reduce<<<B, 256, 0, stream>>>(ids, N, hdr, part, out_f, waveChunk);
}

// Round 6
// 241.093 us; speedup vs baseline: 1.1626x; 1.1626x over previous
//
#include <hip/hip_runtime.h>

// GlobalMaxAvgPool: segment max + segment mean, N=2e6, C=128, B=32, ids sorted.
// Memory-bound: 1.03 GB read -> floor ~167 us @ 6.29 TB/s (m13 copy ubench).
// R6 = R4's proven read engine (block-contiguous chunk, 8-row slot interleave,
// plain cached loads, unroll 4, LDS reduce, zero atomics) with ALL boundary
// work made self-contained:
//  - gp_main loads its own 4KB id slice to LDS, finds run boundaries locally
//    (no gp_prep kernel, no cold global binary search, one less graph gap)
//  - gp_reduce consumes only the L2-hot hdr array (binary search on the
//    monotonic per-block first-seg column), never touches ids.

using f32x4 = __attribute__((ext_vector_type(4))) float;
#define INFF __builtin_huge_valf()

#define BLOCKS 2048
#define MAXR   32        // max runs per block == B (ids ascending, <=32 values)

// ws layout: hdr int2[BLOCKS*MAXR] at 0 (512 KB); partials at 1 MB (64 MB)
#define OFF_PART (1u << 20)

// C==128: 32 lanes x float4 = one row; 8 row-slots stride-8 interleave.
// chunk <= 1024 assumed (N<=2M with BLOCKS=2048 -> chunk=977).
__global__ __launch_bounds__(256, 8)
void gp_main(const float* __restrict__ feat, const int* __restrict__ ids,
             int2* __restrict__ hdr, float* __restrict__ part, int N, int chunk) {
    const int t     = threadIdx.x;
    const int slot  = t >> 5;        // 0..7
    const int lane5 = t & 31;
    const int c0    = lane5 * 4;

    __shared__ int   sids[1024];
    __shared__ int   srb[MAXR + 2];  // run boundaries (local row idx)
    __shared__ int   sbuf[MAXR];
    __shared__ int   snb;
    __shared__ float lmax[8][132];   // +4 pad
    __shared__ float lsum[8][132];

    int start = blockIdx.x * chunk;
    int end   = start + chunk;
    if (end > N) end = N;
    int len = end - start;

    if (len <= 0) {
        for (int j = t; j < MAXR; j += 256)
            hdr[blockIdx.x * MAXR + j] = make_int2(0x7fffffff, 0);
        return;
    }

    // local id slice -> LDS (coalesced 4KB, overlapped across 2048 blocks)
    for (int i = t; i < len; i += 256) sids[i] = ids[start + i];
    if (t == 0) snb = 0;
    __syncthreads();

    // boundary detect (parallel; LDS atomic order canonicalized by sort below)
    for (int i = t; i < len; i += 256)
        if (i > 0 && sids[i] != sids[i - 1]) {
            int p = atomicAdd(&snb, 1);   // p <= 30 < MAXR guaranteed (B=32)
            sbuf[p] = i;
        }
    __syncthreads();
    int nb = snb;                         // uniform
    if (t == 0) {
        for (int i2 = 1; i2 < nb; ++i2) { // insertion sort (nb is tiny)
            int v = sbuf[i2]; int j2 = i2 - 1;
            while (j2 >= 0 && sbuf[j2] > v) { sbuf[j2 + 1] = sbuf[j2]; --j2; }
            sbuf[j2 + 1] = v;
        }
        srb[0] = 0;
        for (int i2 = 0; i2 < nb; ++i2) srb[i2 + 1] = sbuf[i2];
        srb[nb + 1] = len;
    }
    __syncthreads();

    const f32x4* __restrict__ frow = reinterpret_cast<const f32x4*>(feat);

    for (int j = 0; j <= nb; ++j) {       // uniform run loop
        int lrs = srb[j], lre = srb[j + 1];
        int seg = sids[lrs];
        int rs = start + lrs, re = start + lre;

        f32x4 vmax = {-INFF, -INFF, -INFF, -INFF};
        f32x4 vsum = {0.f, 0.f, 0.f, 0.f};
        #pragma unroll 4
        for (int r = rs + slot; r < re; r += 8) {
            f32x4 f = frow[(size_t)r * 32 + lane5];   // 16B/lane coalesced
            vmax[0] = fmaxf(vmax[0], f[0]);
            vmax[1] = fmaxf(vmax[1], f[1]);
            vmax[2] = fmaxf(vmax[2], f[2]);
            vmax[3] = fmaxf(vmax[3], f[3]);
            vsum += f;
        }

        // block LDS reduce: 8 contributors per channel
        lmax[slot][c0 + 0] = vmax[0]; lmax[slot][c0 + 1] = vmax[1];
        lmax[slot][c0 + 2] = vmax[2]; lmax[slot][c0 + 3] = vmax[3];
        lsum[slot][c0 + 0] = vsum[0]; lsum[slot][c0 + 1] = vsum[1];
        lsum[slot][c0 + 2] = vsum[2]; lsum[slot][c0 + 3] = vsum[3];
        __syncthreads();

        if (t < 128) {
            float m  = lmax[0][t];
            float su = lsum[0][t];
            #pragma unroll
            for (int s = 1; s < 8; ++s) {
                m   = fmaxf(m, lmax[s][t]);
                su += lsum[s][t];
            }
            size_t base = (size_t)(blockIdx.x * MAXR + j) * 256;
            part[base + t]       = m;
            part[base + 128 + t] = su;
        }
        if (t == 0) hdr[blockIdx.x * MAXR + j] = make_int2(seg, lre - lrs);
        __syncthreads();
    }
    // sentinel unused slots every call (ws not re-poisoned; keep deterministic)
    for (int j = nb + 1 + t; j < MAXR; j += 256)
        hdr[blockIdx.x * MAXR + j] = make_int2(0x7fffffff, 0);
}

// One block per segment. Per-block first-run seg hdr[k*MAXR].x is monotonic in k
// -> binary search the block range, scan with early break (runs ascending).
// hdr/partials are L2-hot (just written). Fixed order -> deterministic.
__global__ void gp_reduce(const int2* __restrict__ hdr,
                          const float* __restrict__ part,
                          float* __restrict__ out, int nblocks) {
    int b = blockIdx.x;
    int t = threadIdx.x;   // t<128: max chan t ; t>=128: sum chan t-128

    // a = max(0, lb(F,b)-1), c = lb(F,b+1)-1  on F[k] = hdr[k*MAXR].x
    int lo = 0, hi = nblocks;
    while (lo < hi) { int mid = (lo + hi) >> 1; if (hdr[mid * MAXR].x < b) lo = mid + 1; else hi = mid; }
    int a = lo > 0 ? lo - 1 : 0;
    int lo2 = lo, hi2 = nblocks;
    while (lo2 < hi2) { int mid = (lo2 + hi2) >> 1; if (hdr[mid * MAXR].x < b + 1) lo2 = mid + 1; else hi2 = mid; }
    int c = lo2 - 1;

    float m  = -INFF;
    float su = 0.f;
    int   cnt = 0;
    for (int k = a; k <= c; ++k) {
        for (int r2 = 0; r2 < MAXR; ++r2) {
            int2 h = hdr[k * MAXR + r2];          // uniform -> broadcast
            if (h.x == b) {
                float v = part[(size_t)(k * MAXR + r2) * 256 + t];
                m   = fmaxf(m, v);    // meaningful when t<128
                su += v;              // meaningful when t>=128
                cnt += h.y;
            } else if (h.x > b) break;            // runs ascending + sentinel
        }
    }
    out[b * 256 + t] = (t < 128) ? m : su / fmaxf((float)cnt, 1.0f);
}

extern "C" void kernel_launch(void* const* d_in, const int* in_sizes, int n_in,
                              void* d_out, int out_size, void* d_ws, size_t ws_size,
                              hipStream_t stream) {
    const float* feat = (const float*)d_in[0];
    const int*   ids  = (const int*)d_in[1];
    int N = in_sizes[1];
    int C = (N > 0) ? (in_sizes[0] / N) : 128;   // 128
    int B = out_size / (2 * C);                  // 32
    float* out_f = (float*)d_out;

    char*  wsb  = (char*)d_ws;
    int2*  hdr  = (int2*)wsb;                    // BLOCKS*MAXR int2 (512 KB)
    float* part = (float*)(wsb + OFF_PART);      // BLOCKS*MAXR*256 floats (64 MB)

    int chunk = (N + BLOCKS - 1) / BLOCKS;       // 977

    gp_main<<<BLOCKS, 256, 0, stream>>>(feat, ids, hdr, part, N, chunk);
    gp_reduce<<<B, 256, 0, stream>>>(hdr, part, out_f, BLOCKS);
}